// Round 6
// baseline (252.561 us; speedup 1.0000x reference)
//
#include <hip/hip_runtime.h>
#include <hip/hip_bf16.h>

#define NN 10000
#define NE 160000
#define NH 32
#define LRELU_SLOPE 0.2f
#define SM_EPS 1e-16f
#define SM_SHIFT 16.0f

typedef __hip_bfloat16 bf16;
typedef __attribute__((ext_vector_type(8))) __bf16 bf16x8;
typedef __attribute__((ext_vector_type(4))) float f32x4;

__device__ __forceinline__ float bits2f(unsigned int u16) {
    union { unsigned int u; float f; } v; v.u = u16 << 16; return v.f;
}
__device__ __forceinline__ void loadbf8(const bf16* __restrict__ p, float f[8]) {
    uint4 v = *reinterpret_cast<const uint4*>(p);
    f[0] = bits2f(v.x & 0xffffu); f[1] = bits2f(v.x >> 16);
    f[2] = bits2f(v.y & 0xffffu); f[3] = bits2f(v.y >> 16);
    f[4] = bits2f(v.z & 0xffffu); f[5] = bits2f(v.z >> 16);
    f[6] = bits2f(v.w & 0xffffu); f[7] = bits2f(v.w >> 16);
}

// ---------------- edge dtype detect + normalize (+ deg zero) ----------------
__global__ void k_edge_detect(const unsigned int* __restrict__ raw, int* __restrict__ flag) {
    if (threadIdx.x == 0 && blockIdx.x == 0) {
        int z = 1;
        for (int i = 1; i < 32; i += 2) z &= (raw[i] == 0u);
        *flag = z;   // 1 => int64
    }
}
__global__ void k_edge_norm(const int* __restrict__ raw, const int* __restrict__ flag,
                            int* __restrict__ srcv, int* __restrict__ dstv, int* __restrict__ deg) {
    int e = blockIdx.x * blockDim.x + threadIdx.x;
    if (e < NN) deg[e] = 0;
    if (e >= NE) return;
    if (*flag) { srcv[e] = raw[2 * e]; dstv[e] = raw[2 * (NE + e)]; }
    else       { srcv[e] = raw[e];     dstv[e] = raw[NE + e]; }
}

// ---------------- CSR build ----------------
__global__ void k_hist(const int* __restrict__ dstv, int* __restrict__ deg) {
    int e = blockIdx.x * blockDim.x + threadIdx.x;
    if (e < NE) atomicAdd(&deg[dstv[e]], 1);
}
// shfl-based scan, 1024 threads, 10 chunks
__global__ void k_scan(const int* __restrict__ deg, int* __restrict__ offs, int* __restrict__ cursor) {
    __shared__ int wsum[16], wpre[16];
    __shared__ int base;
    const int tid = threadIdx.x, lane = tid & 63, wid = tid >> 6;
    if (tid == 0) base = 0;
    __syncthreads();
    for (int chunk = 0; chunk < NN; chunk += 1024) {
        int idx = chunk + tid;
        int v = (idx < NN) ? deg[idx] : 0;
        int s = v;
        #pragma unroll
        for (int off = 1; off < 64; off <<= 1) {
            int t = __shfl_up(s, off);
            if (lane >= off) s += t;
        }
        if (lane == 63) wsum[wid] = s;
        __syncthreads();
        if (wid == 0) {
            int ws = (lane < 16) ? wsum[lane] : 0;
            #pragma unroll
            for (int off = 1; off < 16; off <<= 1) {
                int t = __shfl_up(ws, off);
                if (lane >= off) ws += t;
            }
            if (lane < 16) wpre[lane] = ws;
        }
        __syncthreads();
        int wbase = (wid == 0) ? 0 : wpre[wid - 1];
        int excl = base + wbase + s - v;
        if (idx < NN) { offs[idx] = excl; cursor[idx] = excl; }
        int total = wpre[15];
        __syncthreads();
        if (tid == 0) base += total;
        __syncthreads();
    }
    if (tid == 0) offs[NN] = base;
}
__global__ void k_scatter(const int* __restrict__ srcv, const int* __restrict__ dstv,
                          int* __restrict__ cursor, int* __restrict__ srcs) {
    int e = blockIdx.x * blockDim.x + threadIdx.x;
    if (e < NE) {
        int p = atomicAdd(&cursor[dstv[e]], 1);
        srcs[p] = srcv[e];
    }
}

// ---------------- fused prep: cast X, transpose W1, transpose W2 ----------------
__global__ void k_prep(const float* __restrict__ X, bf16* __restrict__ Xb,
                       const float* __restrict__ W1, bf16* __restrict__ Wt1,
                       const float* __restrict__ W2, bf16* __restrict__ Wt2) {
    int i = blockIdx.x * blockDim.x + threadIdx.x;
    if (i < NN * 128) { Xb[i] = __float2bfloat16(X[i]); return; }
    i -= NN * 128;
    if (i < 128 * 2048) {
        int k = i / 2048, m = i - k * 2048;
        Wt1[(size_t)m * 128 + k] = __float2bfloat16(W1[i]);
        return;
    }
    i -= 128 * 2048;
    if (i < 64 * 1024) {
        int k = i / 1024, m = i - k * 1024;
        Wt2[(size_t)m * 64 + k] = __float2bfloat16(W2[i]);
    }
}

// ------- MFMA GEMM: XPB[n, M](bf16) = Xb[n, :K] @ Wt^T; fused alpha dots -------
template<int K, int M, int C>
__global__ __launch_bounds__(256) void k_gemm_mfma(
        const bf16* __restrict__ Xb, const bf16* __restrict__ Wt,
        const float* __restrict__ Asrc, const float* __restrict__ Adst,
        bf16* __restrict__ XPB, float* __restrict__ aS, float* __restrict__ aD) {
    constexpr int BM = 64, BN = 128;
    constexpr int KB = K * 2;            // LDS row bytes
    constexpr int NHB = BN / C;          // heads per block (2 or 4)
    constexpr int WPH = C / 32;          // waves per head  (2 or 1)
    __shared__ char lds[(BM + BN) * KB];
    __shared__ float sredS[4][BM], sredD[4][BM];
    char* lA = lds;
    char* lB = lds + BM * KB;

    const int tid = threadIdx.x;
    const int wv = tid >> 6, ln = tid & 63;
    const int lrow = ln & 15, lkb = ln >> 4;
    const int brow = blockIdx.x * BM;
    const int bcol = blockIdx.y * BN;

    #pragma unroll
    for (int c = 0; c < BM * K / 8 / 256; c++) {
        int it = c * 256 + tid;
        int r = it / (K / 8), kc = (it % (K / 8)) * 8;
        int node = brow + r;
        uint4 v = make_uint4(0u, 0u, 0u, 0u);
        if (node < NN) v = *reinterpret_cast<const uint4*>(&Xb[(size_t)node * K + kc]);
        *reinterpret_cast<uint4*>(lA + ((r * KB + kc * 2) ^ ((r & 7) << 4))) = v;
    }
    #pragma unroll
    for (int c = 0; c < BN * K / 8 / 256; c++) {
        int it = c * 256 + tid;
        int r = it / (K / 8), kc = (it % (K / 8)) * 8;
        uint4 v = *reinterpret_cast<const uint4*>(&Wt[(size_t)(bcol + r) * K + kc]);
        *reinterpret_cast<uint4*>(lB + ((r * KB + kc * 2) ^ ((r & 7) << 4))) = v;
    }
    __syncthreads();

    f32x4 acc[4][2];
    #pragma unroll
    for (int mi = 0; mi < 4; mi++)
        #pragma unroll
        for (int nj = 0; nj < 2; nj++) acc[mi][nj] = (f32x4){0.f, 0.f, 0.f, 0.f};

    #pragma unroll
    for (int ks = 0; ks < K / 32; ks++) {
        const int k0 = ks * 32 + lkb * 8;
        bf16x8 af[4], bfr[2];
        #pragma unroll
        for (int mi = 0; mi < 4; mi++) {
            int r = mi * 16 + lrow;
            af[mi] = *reinterpret_cast<const bf16x8*>(lA + ((r * KB + k0 * 2) ^ ((r & 7) << 4)));
        }
        #pragma unroll
        for (int nj = 0; nj < 2; nj++) {
            int r = wv * 32 + nj * 16 + lrow;
            bfr[nj] = *reinterpret_cast<const bf16x8*>(lB + ((r * KB + k0 * 2) ^ ((r & 7) << 4)));
        }
        #pragma unroll
        for (int mi = 0; mi < 4; mi++)
            #pragma unroll
            for (int nj = 0; nj < 2; nj++)
                acc[mi][nj] = __builtin_amdgcn_mfma_f32_16x16x32_bf16(af[mi], bfr[nj], acc[mi][nj], 0, 0, 0);
    }

    // epilogue: D col = lane&15, row = (lane>>4)*4 + reg  [m89]
    float ar0 = Asrc[bcol + wv * 32 + lrow];
    float ar1 = Asrc[bcol + wv * 32 + 16 + lrow];
    float ad0 = Adst[bcol + wv * 32 + lrow];
    float ad1 = Adst[bcol + wv * 32 + 16 + lrow];

    #pragma unroll
    for (int mi = 0; mi < 4; mi++) {
        #pragma unroll
        for (int r = 0; r < 4; r++) {
            int rowl = mi * 16 + lkb * 4 + r;
            int row = brow + rowl;
            if (row < NN) {
                XPB[(size_t)row * M + bcol + wv * 32 + lrow]      = __float2bfloat16(acc[mi][0][r]);
                XPB[(size_t)row * M + bcol + wv * 32 + 16 + lrow] = __float2bfloat16(acc[mi][1][r]);
            }
            float vs = acc[mi][0][r] * ar0 + acc[mi][1][r] * ar1;
            float vd = acc[mi][0][r] * ad0 + acc[mi][1][r] * ad1;
            vs += __shfl_xor(vs, 1); vd += __shfl_xor(vd, 1);
            vs += __shfl_xor(vs, 2); vd += __shfl_xor(vd, 2);
            vs += __shfl_xor(vs, 4); vd += __shfl_xor(vd, 4);
            vs += __shfl_xor(vs, 8); vd += __shfl_xor(vd, 8);
            if (lrow == 0) {
                sredS[wv][rowl] = vs;
                sredD[wv][rowl] = vd;
            }
        }
    }
    __syncthreads();
    if (tid < BM) {
        int node = brow + tid;
        if (node < NN) {
            #pragma unroll
            for (int hb = 0; hb < NHB; hb++) {
                float ss = 0.f, dd = 0.f;
                #pragma unroll
                for (int w = 0; w < WPH; w++) {
                    ss += sredS[hb * WPH + w][tid];
                    dd += sredD[hb * WPH + w][tid];
                }
                int h = bcol / C + hb;
                aS[node * NH + h] = ss;
                aD[node * NH + h] = dd;
            }
        }
    }
}

// ------- XCD-sliced fused softmax+aggregation -------
// One wave = (node, 128-col slice). slice = blockIdx%8 -> XCD binding keeps the
// xpb column slice (2.56 MB) resident in that XCD's L2. Barrier/LDS-free:
// el-reduce via shfl_xor(16,32); head-fold via shfl_xor(8[,4]); writes
// normalized per-slice partial P[sg][node][C].
template<int C>
__global__ __launch_bounds__(256) void k_agg_slice(
        const bf16* __restrict__ XPB, const float* __restrict__ aS,
        const float* __restrict__ aD, const int* __restrict__ offs,
        const int* __restrict__ srcs, float* __restrict__ P, int sg0) {
    constexpr int M = NH * C;       // xpb row length
    constexpr int HPS = 128 / C;    // heads per 128-col slice (2 or 4)
    constexpr int CGH = C / 8;      // col-groups per head (8 or 4)
    const int sg = sg0 + (blockIdx.x & 7);
    const int wid = threadIdx.x >> 6, lane = threadIdx.x & 63;
    const int node = (blockIdx.x >> 3) * 4 + wid;
    const int cg = lane & 15, el = lane >> 4;
    const int hl = cg / CGH;
    const int h = sg * HPS + hl;
    const int col = sg * 128 + cg * 8;
    const int beg = offs[node], end = offs[node + 1];
    const float ad = aD[node * NH + h];
    float acc[8];
    #pragma unroll
    for (int j = 0; j < 8; j++) acc[j] = 0.f;
    float ssum = 0.f;
    for (int i = beg + el; i < end; i += 4) {
        int s = srcs[i];
        float sc = aS[s * NH + h] + ad;
        sc = (sc >= 0.f) ? sc : LRELU_SLOPE * sc;
        float p = __expf(sc - SM_SHIFT);
        ssum += p;
        float xv[8];
        loadbf8(&XPB[(size_t)s * M + col], xv);
        #pragma unroll
        for (int j = 0; j < 8; j++) acc[j] = fmaf(p, xv[j], acc[j]);
    }
    // reduce across the 4 edge-lanes (lane bits 4,5)
    #pragma unroll
    for (int j = 0; j < 8; j++) {
        acc[j] += __shfl_xor(acc[j], 16);
        acc[j] += __shfl_xor(acc[j], 32);
    }
    ssum += __shfl_xor(ssum, 16);
    ssum += __shfl_xor(ssum, 32);
    float r = 1.f / (ssum + SM_EPS);
    #pragma unroll
    for (int j = 0; j < 8; j++) acc[j] *= r;     // per-head normalize BEFORE head-fold
    // fold the slice's heads onto shared output dims (cg bit 3 [, bit 2])
    #pragma unroll
    for (int j = 0; j < 8; j++) acc[j] += __shfl_xor(acc[j], 8);
    if constexpr (HPS == 4) {
        #pragma unroll
        for (int j = 0; j < 8; j++) acc[j] += __shfl_xor(acc[j], 4);
    }
    if (el == 0 && cg < CGH) {
        float* dst = &P[((size_t)sg * NN + node) * C + cg * 8];
        *reinterpret_cast<float4*>(dst)     = make_float4(acc[0], acc[1], acc[2], acc[3]);
        *reinterpret_cast<float4*>(dst + 4) = make_float4(acc[4], acc[5], acc[6], acc[7]);
    }
}

// ------- slice-sum + head-mean + bias + ELU (+ z1 bf16 copy) -------
template<int C, int NS, bool WZ>
__global__ void k_reduce(const float* __restrict__ P, const float* __restrict__ bias,
                         float* __restrict__ out, int col0, bf16* __restrict__ z1b) {
    const int tid = threadIdx.x;
    const int node = blockIdx.x * (256 / C) + tid / C;
    const int c = tid % C;
    float s = 0.f;
    #pragma unroll
    for (int sg = 0; sg < NS; sg++) s += P[((size_t)sg * NN + node) * C + c];
    s = s * (1.0f / NH) + bias[c];
    s = (s > 0.f) ? s : expm1f(s);
    out[(size_t)node * 96 + col0 + c] = s;
    if constexpr (WZ) z1b[(size_t)node * C + c] = __float2bfloat16(s);
}

extern "C" void kernel_launch(void* const* d_in, const int* in_sizes, int n_in,
                              void* d_out, int out_size, void* d_ws, size_t ws_size,
                              hipStream_t stream) {
    const float* x   = (const float*)d_in[0];
    const int*   ei  = (const int*)d_in[1];
    const float* W1  = (const float*)d_in[2];
    const float* as1 = (const float*)d_in[3];
    const float* ad1 = (const float*)d_in[4];
    const float* b1  = (const float*)d_in[5];
    const float* W2  = (const float*)d_in[6];
    const float* as2 = (const float*)d_in[7];
    const float* ad2 = (const float*)d_in[8];
    const float* b2  = (const float*)d_in[9];
    float* out = (float*)d_out;

    char* w = (char*)d_ws;
    size_t off = 0;
    auto alloc = [&](size_t bytes) -> void* {
        void* p = w + off;
        off = (off + bytes + 255) & ~(size_t)255;
        return p;
    };
    bf16*  xpb    = (bf16*)alloc((size_t)NN * 2048 * 2);    // reused for layer2
    float* aS     = (float*)alloc((size_t)NN * NH * 4);
    float* aD     = (float*)alloc((size_t)NN * NH * 4);
    float* P1     = (float*)alloc((size_t)16 * NN * 64 * 4);
    float* P2     = (float*)alloc((size_t)8 * NN * 32 * 4);
    int*   deg    = (int*)alloc((size_t)NN * 4);
    int*   cursor = (int*)alloc((size_t)NN * 4);
    int*   offs   = (int*)alloc((size_t)(NN + 1) * 4);
    int*   srcs   = (int*)alloc((size_t)NE * 4);
    int*   srcv   = (int*)alloc((size_t)NE * 4);
    int*   dstv   = (int*)alloc((size_t)NE * 4);
    bf16*  Xb     = (bf16*)alloc((size_t)NN * 128 * 2);
    bf16*  Wt1    = (bf16*)alloc((size_t)2048 * 128 * 2);
    bf16*  Wt2    = (bf16*)alloc((size_t)1024 * 64 * 2);
    bf16*  z1b    = (bf16*)alloc((size_t)NN * 64 * 2);
    int*   eflag  = (int*)alloc(256);
    (void)ws_size; (void)in_sizes; (void)n_in; (void)out_size;

    // edges + CSR
    k_edge_detect<<<1, 64, 0, stream>>>((const unsigned int*)ei, eflag);
    k_edge_norm<<<(NE + 255) / 256, 256, 0, stream>>>(ei, eflag, srcv, dstv, deg);
    k_hist<<<NE / 256, 256, 0, stream>>>(dstv, deg);
    k_scan<<<1, 1024, 0, stream>>>(deg, offs, cursor);
    k_scatter<<<NE / 256, 256, 0, stream>>>(srcv, dstv, cursor, srcs);

    // bf16 operand prep (one kernel)
    k_prep<<<(NN * 128 + 128 * 2048 + 64 * 1024 + 255) / 256, 256, 0, stream>>>(
        x, Xb, W1, Wt1, W2, Wt2);

    // ---- Layer 1: K=128, C=64, M=2048 ----
    k_gemm_mfma<128, 2048, 64><<<dim3((NN + 63) / 64, 2048 / 128), 256, 0, stream>>>(
        Xb, Wt1, as1, ad1, xpb, aS, aD);
    k_agg_slice<64><<<(NN / 4) * 8, 256, 0, stream>>>(xpb, aS, aD, offs, srcs, P1, 0);
    k_agg_slice<64><<<(NN / 4) * 8, 256, 0, stream>>>(xpb, aS, aD, offs, srcs, P1, 8);
    k_reduce<64, 16, true><<<NN / 4, 256, 0, stream>>>(P1, b1, out, 0, z1b);

    // ---- Layer 2: K=64, C=32, M=1024 ----
    k_gemm_mfma<64, 1024, 32><<<dim3((NN + 63) / 64, 1024 / 128), 256, 0, stream>>>(
        z1b, Wt2, as2, ad2, xpb, aS, aD);
    k_agg_slice<32><<<(NN / 4) * 8, 256, 0, stream>>>(xpb, aS, aD, offs, srcs, P2, 0);
    k_reduce<32, 8, false><<<NN / 8, 256, 0, stream>>>(P2, b2, out, 64, nullptr);
}